// Round 5
// baseline (564.911 us; speedup 1.0000x reference)
//
#include <hip/hip_runtime.h>
#include <hip/hip_bf16.h>

#define H      256
#define CAP    64
#define GRID12 512

typedef _Float16 f16x8 __attribute__((ext_vector_type(8)));
typedef float    f32x4 __attribute__((ext_vector_type(4)));

// ---------------------------------------------------------------- K0: pack weights
// aW1F fp16 fragment-ordered: chunk e8 = ((nt*8+kk)*64+l):
//   j = nt*16 + (l&15), k = kk*32 + (l>>4)*8 + e  -> aW1[k*128+j]
__global__ __launch_bounds__(256) void k0_pack(
    const float* __restrict__ aW1, const float* __restrict__ gW1,
    const float* __restrict__ gW2,
    _Float16* __restrict__ aW1F, float* __restrict__ gW1P, float* __restrict__ gW2P)
{
    int idx = blockIdx.x * 256 + threadIdx.x;
    int stride = gridDim.x * 256;
    for (int e8 = idx; e8 < 4096; e8 += stride) {
        int l = e8 & 63, kknt = e8 >> 6;
        int kk = kknt & 7, nt = kknt >> 3;
        int j = nt*16 + (l & 15);
        int kbase = kk*32 + (l >> 4)*8;
        f16x8 v;
        #pragma unroll
        for (int e = 0; e < 8; ++e) v[e] = (_Float16)aW1[(kbase + e)*128 + j];
        *reinterpret_cast<f16x8*>(aW1F + e8*8) = v;
    }
    for (int e = idx; e < 64*256*4; e += stride) {
        int s = e & 3, j = (e >> 2) & 255, kq = e >> 10;
        gW1P[e] = gW1[(kq*4+s)*256 + j];
    }
    for (int e = idx; e < 64*128*4; e += stride) {
        int s = e & 3, j = (e >> 2) & 127, kq = e >> 9;
        gW2P[e] = gW2[(kq*4+s)*128 + j];
    }
}

// ---------------------------------------------------------------- K2a: segment starts
__global__ __launch_bounds__(256) void k2a_starts(
    const int* __restrict__ batch, int* __restrict__ starts, int N, int M)
{
    int i = blockIdx.x * 256 + threadIdx.x;
    if (i >= N) return;
    int b = batch[i];
    if (i == 0) {
        for (int m = 0; m <= b; ++m) starts[m] = 0;
    } else {
        int p = batch[i-1];
        for (int m = p + 1; m <= b; ++m) starts[m] = i;
    }
    if (i == N - 1) {
        for (int m = b + 1; m <= M; ++m) starts[m] = N;
    }
}

// ---------------------------------------------------------------- K12: fused, persistent, pipelined,
// single HBM pass: fp32 chunk in LDS serves both MFMA (cvt on read) and fp32 pool.
__global__ __launch_bounds__(256) void k12_fused(
    const float* __restrict__ emb, const int* __restrict__ starts,
    const _Float16* __restrict__ aW1F, const float* __restrict__ ab1,
    const float* __restrict__ aW2, const float* __restrict__ ab2,
    float* __restrict__ mol, int M)
{
    __shared__ __align__(16) float ef[CAP * H];   // 64 KB fp32, XOR-swizzled
    __shared__ float pr[4][CAP];
    __shared__ float lgs[CAP];
    __shared__ float wl[CAP];

    const int t = threadIdx.x, w = t >> 6, l = t & 63;
    char* ldsb = reinterpret_cast<char*>(ef);
    const f32x4 zero = {0.f, 0.f, 0.f, 0.f};

    // persistent B-fragments: wave w owns hidden cols [32w, 32w+32)
    f16x8 bf[2][8];
    #pragma unroll
    for (int nt2 = 0; nt2 < 2; ++nt2)
        #pragma unroll
        for (int kk = 0; kk < 8; ++kk)
            bf[nt2][kk] = *reinterpret_cast<const f16x8*>(
                aW1F + (size_t)(((2*w + nt2)*8 + kk)*64 + l)*8);

    float b1v[2], w2v[2];
    #pragma unroll
    for (int nt2 = 0; nt2 < 2; ++nt2) {
        int j = 32*w + nt2*16 + (l & 15);
        b1v[nt2] = ab1[j];
        w2v[nt2] = aW2[j];
    }
    const float bo = ab2[0];

    // first non-empty molecule for this block
    int m = blockIdx.x, start = 0, end = 0;
    for (;;) {
        if (m >= M) return;
        start = starts[m]; end = starts[m + 1];
        if (start < end) break;
        mol[(size_t)m*H + t] = 0.f;
        m += GRID12;
    }

    int c0 = start;
    int cc = min(CAP, end - c0);
    float4 pv[16];

    // static-unrolled predicated issue: 16 float4 loads in flight (T14)
#define ISSUE(C0, CC) do {                                                      \
    _Pragma("unroll")                                                           \
    for (int j = 0; j < 8; ++j) {                                               \
        int ci = t + j*256;                                                     \
        int r = ci >> 5, c8 = ci & 31;                                          \
        int rr = r < (CC) ? r : (CC) - 1;                                       \
        const float4* pp = reinterpret_cast<const float4*>(                     \
            emb + (size_t)((C0) + rr)*H) + c8*2;                                \
        pv[2*j] = pp[0]; pv[2*j+1] = pp[1];                                     \
    } } while (0)

    ISSUE(c0, cc);
    float mx = -INFINITY, s = 0.f, acc = 0.f;

    for (;;) {
        const int  cur_m = m, cur_c0 = c0, cur_cc = cc;
        const bool last_chunk = (c0 + CAP >= end);
        (void)cur_c0;

        __syncthreads();   // prior chunk fully consumed (LDS + wl/lgs)

        // ---- stage pv -> fp32 LDS (swizzled); vmcnt wait lands here
        #pragma unroll
        for (int j = 0; j < 8; ++j) {
            int ci = t + j*256;
            int r = ci >> 5, c8 = ci & 31;
            int b0 = r*1024 + c8*32, swz = (r & 7) << 4;
            *reinterpret_cast<float4*>(ldsb + ( b0        ^ swz)) = pv[2*j];
            *reinterpret_cast<float4*>(ldsb + ((b0 + 16)  ^ swz)) = pv[2*j+1];
        }

        // ---- advance descriptor, issue next chunk's loads (fly during compute)
        int nm = m, nc0 = c0 + CAP, nend = end;
        bool have_next = true;
        if (last_chunk) {
            nm = m + GRID12;
            for (;;) {
                if (nm >= M) { have_next = false; break; }
                int ns = starts[nm], ne = starts[nm + 1];
                if (ns < ne) { nc0 = ns; nend = ne; break; }
                mol[(size_t)nm*H + t] = 0.f;
                nm += GRID12;
            }
        }
        int ncc = 0;
        if (have_next) { ncc = min(CAP, nend - nc0); ISSUE(nc0, ncc); }
        __syncthreads();   // LDS staged

        // ---- phase 1: logits via MFMA (fp32 LDS -> fp16 frags in-register)
        #pragma unroll
        for (int rt = 0; rt < 4; ++rt) {
            int row   = rt*16 + (l & 15);
            int rbase = row*1024 + (l >> 4)*32;
            int swz   = (row & 7) << 4;
            f32x4 a20 = zero, a21 = zero;
            #pragma unroll
            for (int kk = 0; kk < 8; ++kk) {
                int rb = rbase + kk*128;
                float4 a0 = *reinterpret_cast<const float4*>(ldsb + ( rb       ^ swz));
                float4 a1 = *reinterpret_cast<const float4*>(ldsb + ((rb + 16) ^ swz));
                f16x8 af;
                af[0]=(_Float16)a0.x; af[1]=(_Float16)a0.y; af[2]=(_Float16)a0.z; af[3]=(_Float16)a0.w;
                af[4]=(_Float16)a1.x; af[5]=(_Float16)a1.y; af[6]=(_Float16)a1.z; af[7]=(_Float16)a1.w;
                a20 = __builtin_amdgcn_mfma_f32_16x16x32_f16(af, bf[0][kk], a20, 0, 0, 0);
                a21 = __builtin_amdgcn_mfma_f32_16x16x32_f16(af, bf[1][kk], a21, 0, 0, 0);
            }
            #pragma unroll
            for (int r = 0; r < 4; ++r) {
                float h0 = a20[r] + b1v[0]; h0 = h0 > 0.f ? h0 : 0.f;
                float h1 = a21[r] + b1v[1]; h1 = h1 > 0.f ? h1 : 0.f;
                float p = h0*w2v[0] + h1*w2v[1];
                p += __shfl_xor(p, 1, 64);
                p += __shfl_xor(p, 2, 64);
                p += __shfl_xor(p, 4, 64);
                p += __shfl_xor(p, 8, 64);
                if ((l & 15) == 0) pr[w][rt*16 + (l >> 4)*4 + r] = p;
            }
        }
        __syncthreads();
        if (t < CAP) lgs[t] = pr[0][t] + pr[1][t] + pr[2][t] + pr[3][t] + bo;
        __syncthreads();

        // ---- phase 2: online softmax update (uniform)
        float lg = (l < cur_cc) ? lgs[l] : -INFINITY;
        float mc = lg;
        mc = fmaxf(mc, __shfl_xor(mc, 1, 64));
        mc = fmaxf(mc, __shfl_xor(mc, 2, 64));
        mc = fmaxf(mc, __shfl_xor(mc, 4, 64));
        mc = fmaxf(mc, __shfl_xor(mc, 8, 64));
        mc = fmaxf(mc, __shfl_xor(mc, 16, 64));
        mc = fmaxf(mc, __shfl_xor(mc, 32, 64));
        float mxn = fmaxf(mx, mc);
        float rsc = __expf(mx - mxn);            // first chunk: exp(-inf)=0
        float e = (l < cur_cc) ? __expf(lg - mxn) : 0.f;
        float sc = e;
        sc += __shfl_xor(sc, 1, 64);
        sc += __shfl_xor(sc, 2, 64);
        sc += __shfl_xor(sc, 4, 64);
        sc += __shfl_xor(sc, 8, 64);
        sc += __shfl_xor(sc, 16, 64);
        sc += __shfl_xor(sc, 32, 64);
        s = s*rsc + sc;
        if (w == 0) wl[l] = e;
        mx = mxn;
        __syncthreads();   // wl ready

        // ---- phase 3: fp32 pool from LDS, thread t owns dim t (no HBM re-read)
        acc *= rsc;
        #pragma unroll
        for (int g = 0; g < CAP; ++g) {
            float ev = *reinterpret_cast<const float*>(
                ldsb + ((g*1024 + t*4) ^ ((g & 7) << 4)));
            acc += wl[g] * ev;   // wl[g] = 0 for g >= cur_cc; pad rows finite dup data
        }

        if (last_chunk) {
            mol[(size_t)cur_m*H + t] = acc / s;
            mx = -INFINITY; s = 0.f; acc = 0.f;
        }
        if (!have_next) return;
        m = nm; c0 = nc0; end = nend; cc = ncc;
    }
#undef ISSUE
}

// ---------------------------------------------------------------- K3: molecule MLP -> out[M]
__global__ __launch_bounds__(256) void k3_mlp(
    const float* __restrict__ mol, const float* __restrict__ gW1P,
    const float* __restrict__ gb1, const float* __restrict__ gW2P,
    const float* __restrict__ gb2, const float* __restrict__ gW3,
    const float* __restrict__ gb3, float* __restrict__ out, int M)
{
    __shared__ __align__(16) float mt[32 * 256];
    __shared__ __align__(16) float g1[32 * 256];
    __shared__ float tmp[4][16];
    int t = threadIdx.x;
    int blk = blockIdx.x;

    #pragma unroll
    for (int i = 0; i < 8; ++i) {
        int f = t + i*256;
        long gidx = (long)blk*2048 + f;
        float4 v = make_float4(0.f,0.f,0.f,0.f);
        if (gidx < (long)M*64) v = reinterpret_cast<const float4*>(mol)[gidx];
        reinterpret_cast<float4*>(mt)[f] = v;
    }
    __syncthreads();

    int j = t & 127, mh = t >> 7;

    float a0[16], a1[16];
    #pragma unroll
    for (int m = 0; m < 16; ++m) { a0[m] = 0.f; a1[m] = 0.f; }
    for (int kq = 0; kq < 64; ++kq) {
        float4 w0 = reinterpret_cast<const float4*>(gW1P)[kq*256 + j];
        float4 w1 = reinterpret_cast<const float4*>(gW1P)[kq*256 + j + 128];
        #pragma unroll
        for (int m = 0; m < 16; ++m) {
            float4 e = *reinterpret_cast<const float4*>(&mt[(mh*16 + m)*256 + kq*4]);
            a0[m] += e.x*w0.x + e.y*w0.y + e.z*w0.z + e.w*w0.w;
            a1[m] += e.x*w1.x + e.y*w1.y + e.z*w1.z + e.w*w1.w;
        }
    }
    {
        float b0 = gb1[j], b1 = gb1[j + 128];
        #pragma unroll
        for (int m = 0; m < 16; ++m) {
            float v0 = a0[m] + b0; v0 = v0 > 0.f ? v0 : 0.f;
            float v1 = a1[m] + b1; v1 = v1 > 0.f ? v1 : 0.f;
            g1[(mh*16 + m)*256 + j]       = v0;
            g1[(mh*16 + m)*256 + j + 128] = v1;
        }
    }
    __syncthreads();

    float a2[16];
    #pragma unroll
    for (int m = 0; m < 16; ++m) a2[m] = 0.f;
    for (int kq = 0; kq < 64; ++kq) {
        float4 w = reinterpret_cast<const float4*>(gW2P)[kq*128 + j];
        #pragma unroll
        for (int m = 0; m < 16; ++m) {
            float4 e = *reinterpret_cast<const float4*>(&g1[(mh*16 + m)*256 + kq*4]);
            a2[m] += e.x*w.x + e.y*w.y + e.z*w.z + e.w*w.w;
        }
    }

    float b2 = gb2[j], w3 = gW3[j];
    float p[16];
    #pragma unroll
    for (int m = 0; m < 16; ++m) {
        float v = a2[m] + b2; v = v > 0.f ? v : 0.f;
        p[m] = v * w3;
    }
    #pragma unroll
    for (int off = 32; off >= 1; off >>= 1) {
        #pragma unroll
        for (int m = 0; m < 16; ++m) p[m] += __shfl_xor(p[m], off, 64);
    }
    int wid = t >> 6;
    if ((t & 63) == 0) {
        #pragma unroll
        for (int m = 0; m < 16; ++m) tmp[wid][m] = p[m];
    }
    __syncthreads();
    if (t < 32) {
        int om = blk*32 + t;
        if (om < M) out[om] = tmp[(t >> 4)*2][t & 15] + tmp[(t >> 4)*2 + 1][t & 15] + gb3[0];
    }
}

// ---------------------------------------------------------------- launch
extern "C" void kernel_launch(void* const* d_in, const int* in_sizes, int n_in,
                              void* d_out, int out_size, void* d_ws, size_t ws_size,
                              hipStream_t stream) {
    const float* emb  = (const float*)d_in[0];
    const int*   batch= (const int*)d_in[1];
    const float* aW1  = (const float*)d_in[3];
    const float* ab1  = (const float*)d_in[4];
    const float* aW2  = (const float*)d_in[5];
    const float* ab2  = (const float*)d_in[6];
    const float* gW1  = (const float*)d_in[7];
    const float* gb1  = (const float*)d_in[8];
    const float* gW2  = (const float*)d_in[9];
    const float* gb2  = (const float*)d_in[10];
    const float* gW3  = (const float*)d_in[11];
    const float* gb3  = (const float*)d_in[12];
    float* outp = (float*)d_out;

    int N = in_sizes[0] / H;
    int M = out_size;

    char* ws = (char*)d_ws;
    size_t off = 0;
    float*     mol    = (float*)(ws + off);    off += (8u<<20);
    _Float16*  aW1F   = (_Float16*)(ws + off); off += 65536;
    float*     gW1P   = (float*)(ws + off);    off += 262144;
    float*     gW2P   = (float*)(ws + off);    off += 131072;
    int*       starts = (int*)(ws + off);      off += (size_t)(M+1)*4;

    int g12 = M < GRID12 ? M : GRID12;

    k0_pack<<<64, 256, 0, stream>>>(aW1, gW1, gW2, aW1F, gW1P, gW2P);
    k2a_starts<<<(N + 255)/256, 256, 0, stream>>>(batch, starts, N, M);
    k12_fused<<<g12, 256, 0, stream>>>(emb, starts, aW1F, ab1, aW2, ab2, mol, M);
    k3_mlp<<<(M + 31)/32, 256, 0, stream>>>(mol, gW1P, gb1, gW2P, gb2, gW3, gb3, outp, M);
}

// Round 6
// 253.974 us; speedup vs baseline: 2.2243x; 2.2243x over previous
//
#include <hip/hip_runtime.h>
#include <hip/hip_bf16.h>

#define H      256
#define CAP    64
#define GRID12 512

typedef _Float16 f16x8 __attribute__((ext_vector_type(8)));
typedef float    f32x4 __attribute__((ext_vector_type(4)));

#define AS3(p) ((__attribute__((address_space(3))) void*)(p))
#define AS1(p) ((const __attribute__((address_space(1))) void*)(p))

// ---------------------------------------------------------------- K0: pack weights
// aW1F fp16 fragment-ordered: chunk e8 = ((nt*8+kk)*64+l):
//   j = nt*16 + (l&15), k = kk*32 + (l>>4)*8 + e  -> aW1[k*128+j]
__global__ __launch_bounds__(256) void k0_pack(
    const float* __restrict__ aW1, const float* __restrict__ gW1,
    const float* __restrict__ gW2,
    _Float16* __restrict__ aW1F, float* __restrict__ gW1P, float* __restrict__ gW2P)
{
    int idx = blockIdx.x * 256 + threadIdx.x;
    int stride = gridDim.x * 256;
    for (int e8 = idx; e8 < 4096; e8 += stride) {
        int l = e8 & 63, kknt = e8 >> 6;
        int kk = kknt & 7, nt = kknt >> 3;
        int j = nt*16 + (l & 15);
        int kbase = kk*32 + (l >> 4)*8;
        f16x8 v;
        #pragma unroll
        for (int e = 0; e < 8; ++e) v[e] = (_Float16)aW1[(kbase + e)*128 + j];
        *reinterpret_cast<f16x8*>(aW1F + e8*8) = v;
    }
    for (int e = idx; e < 64*256*4; e += stride) {
        int s = e & 3, j = (e >> 2) & 255, kq = e >> 10;
        gW1P[e] = gW1[(kq*4+s)*256 + j];
    }
    for (int e = idx; e < 64*128*4; e += stride) {
        int s = e & 3, j = (e >> 2) & 127, kq = e >> 9;
        gW2P[e] = gW2[(kq*4+s)*128 + j];
    }
}

// ---------------------------------------------------------------- K2a: segment starts
__global__ __launch_bounds__(256) void k2a_starts(
    const int* __restrict__ batch, int* __restrict__ starts, int N, int M)
{
    int i = blockIdx.x * 256 + threadIdx.x;
    if (i >= N) return;
    int b = batch[i];
    if (i == 0) {
        for (int m = 0; m <= b; ++m) starts[m] = 0;
    } else {
        int p = batch[i-1];
        for (int m = p + 1; m <= b; ++m) starts[m] = i;
    }
    if (i == N - 1) {
        for (int m = b + 1; m <= M; ++m) starts[m] = N;
    }
}

// ---------------------------------------------------------------- K12: fused, persistent,
// async global->LDS staging (pre-swizzled source, linear LDS dest, swizzled reads).
// Single HBM pass: fp32 chunk serves MFMA (cvt on read) and exact fp32 pool.
__global__ __launch_bounds__(256) void k12_fused(
    const float* __restrict__ emb, const int* __restrict__ starts,
    const _Float16* __restrict__ aW1F, const float* __restrict__ ab1,
    const float* __restrict__ aW2, const float* __restrict__ ab2,
    float* __restrict__ mol, int M)
{
    __shared__ __align__(16) float ef[CAP * H];   // 64 KB fp32
    __shared__ float pr[4][CAP];
    __shared__ float lgs[CAP];
    __shared__ float wl[CAP];

    const int t = threadIdx.x, w = t >> 6, l = t & 63;
    char* ldsb = reinterpret_cast<char*>(ef);
    const f32x4 zero = {0.f, 0.f, 0.f, 0.f};

    // persistent B-fragments: wave w owns hidden cols [32w, 32w+32)
    f16x8 bf[2][8];
    #pragma unroll
    for (int nt2 = 0; nt2 < 2; ++nt2)
        #pragma unroll
        for (int kk = 0; kk < 8; ++kk)
            bf[nt2][kk] = *reinterpret_cast<const f16x8*>(
                aW1F + (size_t)(((2*w + nt2)*8 + kk)*64 + l)*8);

    float b1v[2], w2v[2];
    #pragma unroll
    for (int nt2 = 0; nt2 < 2; ++nt2) {
        int j = 32*w + nt2*16 + (l & 15);
        b1v[nt2] = ab1[j];
        w2v[nt2] = aW2[j];
    }
    const float bo = ab2[0];

    // first non-empty molecule for this block
    int m = blockIdx.x, start = 0, end = 0;
    for (;;) {
        if (m >= M) return;
        start = starts[m]; end = starts[m + 1];
        if (start < end) break;
        mol[(size_t)m*H + t] = 0.f;
        m += GRID12;
    }

    int c0 = start;
    int cc = min(CAP, end - c0);
    float mx = -INFINITY, s = 0.f, acc = 0.f;

    for (;;) {
        const int  cur_m = m, cur_cc = cc;
        const bool last_chunk = (c0 + CAP >= end);

        __syncthreads();   // prior chunk fully consumed (LDS + wl/lgs)

        // ---- async stage: wave w stages rows [16w, 16w+16); one 1KB row per
        // instruction; global source pre-swizzled so LDS-linear == swizzled layout
        #pragma unroll
        for (int i = 0; i < 16; ++i) {
            int r = w*16 + i;
            if (r < cc) {
                const char* gs = reinterpret_cast<const char*>(emb + (size_t)(c0 + r)*H)
                               + ((l*16) ^ ((r & 7) << 4));
#if __has_builtin(__builtin_amdgcn_global_load_lds)
                __builtin_amdgcn_global_load_lds(AS1(gs), AS3(ldsb + r*1024), 16, 0, 0);
#else
                *reinterpret_cast<float4*>(ldsb + r*1024 + l*16) =
                    *reinterpret_cast<const float4*>(gs);
#endif
            }
        }

        // ---- advance descriptor while loads fly
        int nm = m, nc0 = c0 + CAP, nend = end;
        bool have_next = true;
        if (last_chunk) {
            nm = m + GRID12;
            for (;;) {
                if (nm >= M) { have_next = false; break; }
                int ns = starts[nm], ne = starts[nm + 1];
                if (ns < ne) { nc0 = ns; nend = ne; break; }
                mol[(size_t)nm*H + t] = 0.f;
                nm += GRID12;
            }
        }
        int ncc = have_next ? min(CAP, nend - nc0) : 0;
        __syncthreads();   // drains vmcnt -> LDS ready

        // ---- phase 1: logits via MFMA (fp32 LDS -> fp16 frags in-register)
        const int nr = (cur_cc + 15) >> 4;
        for (int rt = 0; rt < nr; ++rt) {
            int row   = rt*16 + (l & 15);
            int rbase = row*1024 + (l >> 4)*32;
            int swz   = (row & 7) << 4;
            f32x4 a20 = zero, a21 = zero;
            #pragma unroll
            for (int kk = 0; kk < 8; ++kk) {
                int rb = rbase + kk*128;
                float4 a0 = *reinterpret_cast<const float4*>(ldsb + ( rb       ^ swz));
                float4 a1 = *reinterpret_cast<const float4*>(ldsb + ((rb + 16) ^ swz));
                f16x8 af;
                af[0]=(_Float16)a0.x; af[1]=(_Float16)a0.y; af[2]=(_Float16)a0.z; af[3]=(_Float16)a0.w;
                af[4]=(_Float16)a1.x; af[5]=(_Float16)a1.y; af[6]=(_Float16)a1.z; af[7]=(_Float16)a1.w;
                a20 = __builtin_amdgcn_mfma_f32_16x16x32_f16(af, bf[0][kk], a20, 0, 0, 0);
                a21 = __builtin_amdgcn_mfma_f32_16x16x32_f16(af, bf[1][kk], a21, 0, 0, 0);
            }
            #pragma unroll
            for (int r = 0; r < 4; ++r) {
                float h0 = a20[r] + b1v[0]; h0 = h0 > 0.f ? h0 : 0.f;
                float h1 = a21[r] + b1v[1]; h1 = h1 > 0.f ? h1 : 0.f;
                float p = h0*w2v[0] + h1*w2v[1];
                p += __shfl_xor(p, 1, 64);
                p += __shfl_xor(p, 2, 64);
                p += __shfl_xor(p, 4, 64);
                p += __shfl_xor(p, 8, 64);
                if ((l & 15) == 0) pr[w][rt*16 + (l >> 4)*4 + r] = p;
            }
        }
        __syncthreads();
        if (t < CAP) lgs[t] = pr[0][t] + pr[1][t] + pr[2][t] + pr[3][t] + bo;
        __syncthreads();

        // ---- phase 2: online softmax update (uniform; pad slots masked)
        float lg = (l < cur_cc) ? lgs[l] : -INFINITY;
        float mc = lg;
        mc = fmaxf(mc, __shfl_xor(mc, 1, 64));
        mc = fmaxf(mc, __shfl_xor(mc, 2, 64));
        mc = fmaxf(mc, __shfl_xor(mc, 4, 64));
        mc = fmaxf(mc, __shfl_xor(mc, 8, 64));
        mc = fmaxf(mc, __shfl_xor(mc, 16, 64));
        mc = fmaxf(mc, __shfl_xor(mc, 32, 64));
        float mxn = fmaxf(mx, mc);
        float rsc = __expf(mx - mxn);            // first chunk: exp(-inf)=0
        float e = (l < cur_cc) ? __expf(lg - mxn) : 0.f;
        float sc = e;
        sc += __shfl_xor(sc, 1, 64);
        sc += __shfl_xor(sc, 2, 64);
        sc += __shfl_xor(sc, 4, 64);
        sc += __shfl_xor(sc, 8, 64);
        sc += __shfl_xor(sc, 16, 64);
        sc += __shfl_xor(sc, 32, 64);
        s = s*rsc + sc;
        if (w == 0) wl[l] = e;
        mx = mxn;
        __syncthreads();   // wl ready

        // ---- phase 3: fp32 pool from LDS, thread t owns dim t (rows < cc only)
        acc *= rsc;
        #pragma unroll 4
        for (int g = 0; g < cur_cc; ++g) {
            float ev = *reinterpret_cast<const float*>(
                ldsb + ((g*1024 + t*4) ^ ((g & 7) << 4)));
            acc += wl[g] * ev;
        }

        if (last_chunk) {
            mol[(size_t)cur_m*H + t] = acc / s;
            mx = -INFINITY; s = 0.f; acc = 0.f;
        }
        if (!have_next) return;
        m = nm; c0 = nc0; end = nend; cc = ncc;
    }
}

// ---------------------------------------------------------------- K3: molecule MLP -> out[M]
__global__ __launch_bounds__(256) void k3_mlp(
    const float* __restrict__ mol, const float* __restrict__ gW1P,
    const float* __restrict__ gb1, const float* __restrict__ gW2P,
    const float* __restrict__ gb2, const float* __restrict__ gW3,
    const float* __restrict__ gb3, float* __restrict__ out, int M)
{
    __shared__ __align__(16) float mt[32 * 256];
    __shared__ __align__(16) float g1[32 * 256];
    __shared__ float tmp[4][16];
    int t = threadIdx.x;
    int blk = blockIdx.x;

    #pragma unroll
    for (int i = 0; i < 8; ++i) {
        int f = t + i*256;
        long gidx = (long)blk*2048 + f;
        float4 v = make_float4(0.f,0.f,0.f,0.f);
        if (gidx < (long)M*64) v = reinterpret_cast<const float4*>(mol)[gidx];
        reinterpret_cast<float4*>(mt)[f] = v;
    }
    __syncthreads();

    int j = t & 127, mh = t >> 7;

    float a0[16], a1[16];
    #pragma unroll
    for (int m = 0; m < 16; ++m) { a0[m] = 0.f; a1[m] = 0.f; }
    for (int kq = 0; kq < 64; ++kq) {
        float4 w0 = reinterpret_cast<const float4*>(gW1P)[kq*256 + j];
        float4 w1 = reinterpret_cast<const float4*>(gW1P)[kq*256 + j + 128];
        #pragma unroll
        for (int m = 0; m < 16; ++m) {
            float4 e = *reinterpret_cast<const float4*>(&mt[(mh*16 + m)*256 + kq*4]);
            a0[m] += e.x*w0.x + e.y*w0.y + e.z*w0.z + e.w*w0.w;
            a1[m] += e.x*w1.x + e.y*w1.y + e.z*w1.z + e.w*w1.w;
        }
    }
    {
        float b0 = gb1[j], b1 = gb1[j + 128];
        #pragma unroll
        for (int m = 0; m < 16; ++m) {
            float v0 = a0[m] + b0; v0 = v0 > 0.f ? v0 : 0.f;
            float v1 = a1[m] + b1; v1 = v1 > 0.f ? v1 : 0.f;
            g1[(mh*16 + m)*256 + j]       = v0;
            g1[(mh*16 + m)*256 + j + 128] = v1;
        }
    }
    __syncthreads();

    float a2[16];
    #pragma unroll
    for (int m = 0; m < 16; ++m) a2[m] = 0.f;
    for (int kq = 0; kq < 64; ++kq) {
        float4 w = reinterpret_cast<const float4*>(gW2P)[kq*128 + j];
        #pragma unroll
        for (int m = 0; m < 16; ++m) {
            float4 e = *reinterpret_cast<const float4*>(&g1[(mh*16 + m)*256 + kq*4]);
            a2[m] += e.x*w.x + e.y*w.y + e.z*w.z + e.w*w.w;
        }
    }

    float b2 = gb2[j], w3 = gW3[j];
    float p[16];
    #pragma unroll
    for (int m = 0; m < 16; ++m) {
        float v = a2[m] + b2; v = v > 0.f ? v : 0.f;
        p[m] = v * w3;
    }
    #pragma unroll
    for (int off = 32; off >= 1; off >>= 1) {
        #pragma unroll
        for (int m = 0; m < 16; ++m) p[m] += __shfl_xor(p[m], off, 64);
    }
    int wid = t >> 6;
    if ((t & 63) == 0) {
        #pragma unroll
        for (int m = 0; m < 16; ++m) tmp[wid][m] = p[m];
    }
    __syncthreads();
    if (t < 32) {
        int om = blk*32 + t;
        if (om < M) out[om] = tmp[(t >> 4)*2][t & 15] + tmp[(t >> 4)*2 + 1][t & 15] + gb3[0];
    }
}

// ---------------------------------------------------------------- launch
extern "C" void kernel_launch(void* const* d_in, const int* in_sizes, int n_in,
                              void* d_out, int out_size, void* d_ws, size_t ws_size,
                              hipStream_t stream) {
    const float* emb  = (const float*)d_in[0];
    const int*   batch= (const int*)d_in[1];
    const float* aW1  = (const float*)d_in[3];
    const float* ab1  = (const float*)d_in[4];
    const float* aW2  = (const float*)d_in[5];
    const float* ab2  = (const float*)d_in[6];
    const float* gW1  = (const float*)d_in[7];
    const float* gb1  = (const float*)d_in[8];
    const float* gW2  = (const float*)d_in[9];
    const float* gb2  = (const float*)d_in[10];
    const float* gW3  = (const float*)d_in[11];
    const float* gb3  = (const float*)d_in[12];
    float* outp = (float*)d_out;

    int N = in_sizes[0] / H;
    int M = out_size;

    char* ws = (char*)d_ws;
    size_t off = 0;
    float*     mol    = (float*)(ws + off);    off += (8u<<20);
    _Float16*  aW1F   = (_Float16*)(ws + off); off += 65536;
    float*     gW1P   = (float*)(ws + off);    off += 262144;
    float*     gW2P   = (float*)(ws + off);    off += 131072;
    int*       starts = (int*)(ws + off);      off += (size_t)(M+1)*4;

    int g12 = M < GRID12 ? M : GRID12;

    k0_pack<<<64, 256, 0, stream>>>(aW1, gW1, gW2, aW1F, gW1P, gW2P);
    k2a_starts<<<(N + 255)/256, 256, 0, stream>>>(batch, starts, N, M);
    k12_fused<<<g12, 256, 0, stream>>>(emb, starts, aW1F, ab1, aW2, ab2, mol, M);
    k3_mlp<<<(M + 31)/32, 256, 0, stream>>>(mol, gW1P, gb1, gW2P, gb2, gW3, gb3, outp, M);
}